// Round 9
// baseline (400.321 us; speedup 1.0000x reference)
//
#include <hip/hip_runtime.h>

// R9: gemm_stats barrier-bound, not occupancy-bound (R8: occ 15->31% but
// VALUBusy stuck at 31%, dur 87->81us). Remove LDS staging + K-loop barriers
// entirely: A rows broadcast-load from global (16B, same addr per half-wave),
// W rows coalesced-load from global (L2-resident). Zero barriers in K-loop ->
// compiler software-pipelines; stats reduce via shfl_xor + 4KB LDS.

#define N_NODES 100000
#define N_EDGES 800000
#define D 128
#define BN_EPS 1e-5f
#define SCAN_NB 98  // ceil(100000/1024)

// ---------------- edge-index dtype hedge (int32 vs int64) ----------------
__global__ void detect_i64(const unsigned int* ei, int* flag) {
    __shared__ int nonzero;
    if (threadIdx.x == 0) nonzero = 0;
    __syncthreads();
    int local = 0;
    for (int i = threadIdx.x; i < 2048; i += 256)
        if (ei[2 * i + 1] != 0u) local = 1;
    if (local) atomicOr(&nonzero, 1);
    __syncthreads();
    if (threadIdx.x == 0) *flag = (nonzero == 0) ? 1 : 0;  // 1 => int64
}

__device__ __forceinline__ int edge_at(const void* ei, int is64, long long pos) {
    if (is64) return (int)((const long long*)ei)[pos];
    return ((const int*)ei)[pos];
}

// ---------------- degree histogram (int atomics) ----------------
__global__ void count_deg_i(const void* ei, const int* __restrict__ flag,
                            int* __restrict__ deg) {
    int is64 = *flag;
    for (int i = blockIdx.x * blockDim.x + threadIdx.x; i < N_EDGES;
         i += gridDim.x * blockDim.x) {
        int d = edge_at(ei, is64, (long long)N_EDGES + i);
        atomicAdd(&deg[d], 1);
    }
}

// ---------------- 3-kernel exclusive scan over deg -> rp ----------------
__global__ __launch_bounds__(256) void scan1(const int* __restrict__ deg,
                                             int* __restrict__ rp,
                                             int* __restrict__ bsum) {
    __shared__ int wsum[4];
    int tid = threadIdx.x;
    int base = blockIdx.x * 1024;
    int v[4];
#pragma unroll
    for (int i = 0; i < 4; ++i) {
        int idx = base + tid * 4 + i;
        v[i] = (idx < N_NODES) ? deg[idx] : 0;
    }
    int tsum = v[0] + v[1] + v[2] + v[3];
    int lane = tid & 63;
    int incl = tsum;
#pragma unroll
    for (int off = 1; off < 64; off <<= 1) {
        int n = __shfl_up(incl, off, 64);
        if (lane >= off) incl += n;
    }
    int wid = tid >> 6;
    if (lane == 63) wsum[wid] = incl;
    __syncthreads();
    int woff = 0;
    for (int w = 0; w < wid; ++w) woff += wsum[w];
    int run = woff + incl - tsum;  // exclusive prefix for this thread
#pragma unroll
    for (int i = 0; i < 4; ++i) {
        int idx = base + tid * 4 + i;
        if (idx < N_NODES) rp[idx] = run;
        run += v[i];
    }
    if (tid == 255) bsum[blockIdx.x] = woff + incl;  // block total
}

__global__ void scan2(int* __restrict__ bsum, int* __restrict__ rp) {
    __shared__ int s[128];
    int t = threadIdx.x;
    if (t < SCAN_NB) s[t] = bsum[t];
    __syncthreads();
    if (t == 0) {
        int run = 0;
        for (int i = 0; i < SCAN_NB; ++i) { int x = s[i]; s[i] = run; run += x; }
        rp[N_NODES] = N_EDGES;
    }
    __syncthreads();
    if (t < SCAN_NB) bsum[t] = s[t];
}

__global__ void scan3(int* __restrict__ rp, const int* __restrict__ bsum,
                      int* __restrict__ fp, const int* __restrict__ deg,
                      float* __restrict__ dis) {
    int idx = blockIdx.x * 256 + threadIdx.x;
    if (idx < N_NODES) {
        int v = rp[idx] + bsum[idx >> 10];
        rp[idx] = v;
        fp[idx] = v;
        dis[idx] = rsqrtf((float)deg[idx] + 1.0f);  // +1 self loop
    }
}

// ---------------- bucket fill: eb[rp[d]..] = (src, dis[s]*dis[d]) ----------------
__global__ void fill_csr(const void* ei, const int* __restrict__ flag,
                         int* __restrict__ fp, const float* __restrict__ dis,
                         int2* __restrict__ eb) {
    int is64 = *flag;
    for (int e = blockIdx.x * blockDim.x + threadIdx.x; e < N_EDGES;
         e += gridDim.x * blockDim.x) {
        int s = edge_at(ei, is64, e);
        int d = edge_at(ei, is64, (long long)N_EDGES + e);
        float coef = dis[s] * dis[d];
        int pos = atomicAdd(&fp[d], 1);
        eb[pos] = make_int2(s, __float_as_int(coef));
    }
}

// ---------------- gather: aggx[d] = sum_e coef*x[s] + dis[d]^2*x[d] ----------------
// one 64-lane wave per node, float2 per lane; 4-deep edge pipeline.
__global__ __launch_bounds__(256) void gather_x(const int* __restrict__ rp,
                                                const int2* __restrict__ eb,
                                                const float* __restrict__ dis,
                                                const float* __restrict__ x,
                                                float* __restrict__ aggx) {
    int lane = threadIdx.x & 63;
    int wid = threadIdx.x >> 6;
    const float2* x2 = (const float2*)x;
    for (int node = blockIdx.x * 4 + wid; node < N_NODES;
         node += gridDim.x * 4) {
        int beg = rp[node], end = rp[node + 1];
        float dd = dis[node];
        float2 xv = x2[(size_t)node * 64 + lane];
        float c2 = dd * dd;
        float a0 = xv.x * c2, a1 = xv.y * c2;
        int j = beg;
        for (; j + 4 <= end; j += 4) {
            int2 e0 = eb[j], e1 = eb[j + 1], e2 = eb[j + 2], e3 = eb[j + 3];
            float2 v0 = x2[(size_t)e0.x * 64 + lane];
            float2 v1 = x2[(size_t)e1.x * 64 + lane];
            float2 v2 = x2[(size_t)e2.x * 64 + lane];
            float2 v3 = x2[(size_t)e3.x * 64 + lane];
            float c0 = __int_as_float(e0.y), c1 = __int_as_float(e1.y);
            float cc = __int_as_float(e2.y), c3 = __int_as_float(e3.y);
            a0 = fmaf(v0.x, c0, a0); a1 = fmaf(v0.y, c0, a1);
            a0 = fmaf(v1.x, c1, a0); a1 = fmaf(v1.y, c1, a1);
            a0 = fmaf(v2.x, cc, a0); a1 = fmaf(v2.y, cc, a1);
            a0 = fmaf(v3.x, c3, a0); a1 = fmaf(v3.y, c3, a1);
        }
        for (; j < end; ++j) {
            int2 e = eb[j];
            float2 v = x2[(size_t)e.x * 64 + lane];
            float c = __int_as_float(e.y);
            a0 = fmaf(v.x, c, a0); a1 = fmaf(v.y, c, a1);
        }
        ((float2*)aggx)[(size_t)node * 64 + lane] = make_float2(a0, a1);
    }
}

// ---------------- in-place GEMM d_out = d_out @ W, fused column stats ----------------
// Zero-LDS-staging, zero-barrier K-loop. A: broadcast float4 loads (all lanes
// of a half-wave read the same 16B). W: coalesced 512B row segments, L2-hot.
// In place race-free: block reads only its own 64 rows before writing them.
__global__ __launch_bounds__(256) void gemm_stats(float* __restrict__ ax,
                                                  const float* __restrict__ Wm,
                                                  float* __restrict__ colsum,
                                                  float* __restrict__ colsumsq) {
    __shared__ float red[8 * 128];  // 4 KB stats-reduce buffer
    int tid = threadIdx.x;
    int row0 = blockIdx.x * 64;
    int tx = tid & 31;
    int ty = tid >> 5;

    const float4* W4 = (const float4*)Wm;

    // per-thread row pointers (clamped; invalid rows masked out of stats/write)
    const float4* arow[8];
    float rmask[8];
#pragma unroll
    for (int r = 0; r < 8; ++r) {
        int gr = row0 + ty * 8 + r;
        int cg = (gr < N_NODES) ? gr : 0;
        arow[r] = (const float4*)(ax + (size_t)cg * 128);
        rmask[r] = (gr < N_NODES) ? 1.0f : 0.0f;
    }

    float acc[8][4] = {};

    for (int kc = 0; kc < 32; ++kc) {  // kc indexes float4 groups: k = 4*kc..4*kc+3
        float4 a8[8];
#pragma unroll
        for (int r = 0; r < 8; ++r) a8[r] = arow[r][kc];
        float4 w[4];
#pragma unroll
        for (int kk = 0; kk < 4; ++kk) w[kk] = W4[(kc * 4 + kk) * 32 + tx];
#pragma unroll
        for (int kk = 0; kk < 4; ++kk) {
#pragma unroll
            for (int r = 0; r < 8; ++r) {
                float av = (kk == 0) ? a8[r].x : (kk == 1) ? a8[r].y
                         : (kk == 2) ? a8[r].z : a8[r].w;
                acc[r][0] = fmaf(av, w[kk].x, acc[r][0]);
                acc[r][1] = fmaf(av, w[kk].y, acc[r][1]);
                acc[r][2] = fmaf(av, w[kk].z, acc[r][2]);
                acc[r][3] = fmaf(av, w[kk].w, acc[r][3]);
            }
        }
    }

    // write back (in place; own rows only, all reads of them already done)
#pragma unroll
    for (int r = 0; r < 8; ++r) {
        int gr = row0 + ty * 8 + r;
        if (gr < N_NODES)
            ((float4*)&ax[(size_t)gr * 128])[tx] =
                make_float4(acc[r][0], acc[r][1], acc[r][2], acc[r][3]);
    }

    // fused BN column stats (masked rows contribute 0)
    float ps[4] = {0.f, 0.f, 0.f, 0.f}, pq[4] = {0.f, 0.f, 0.f, 0.f};
#pragma unroll
    for (int r = 0; r < 8; ++r)
#pragma unroll
        for (int k = 0; k < 4; ++k) {
            float v = acc[r][k] * rmask[r];
            ps[k] += v;
            pq[k] += v * v;
        }
    // combine the wave's two ty-halves: tid and tid^32 share tx
#pragma unroll
    for (int k = 0; k < 4; ++k) {
        ps[k] += __shfl_xor(ps[k], 32);
        pq[k] += __shfl_xor(pq[k], 32);
    }
    int wv = tid >> 6;  // wave id 0..3
    if ((tid & 32) == 0) {
#pragma unroll
        for (int k = 0; k < 4; ++k) {
            red[wv * 128 + tx * 4 + k] = ps[k];
            red[(4 + wv) * 128 + tx * 4 + k] = pq[k];
        }
    }
    __syncthreads();
    if (tid < 128) {
        float s = 0.f, q = 0.f;
#pragma unroll
        for (int w = 0; w < 4; ++w) {
            s += red[w * 128 + tid];
            q += red[(4 + w) * 128 + tid];
        }
        atomicAdd(&colsum[tid], s);
        atomicAdd(&colsumsq[tid], q);
    }
}

// ---------------- BN params (b cancels exactly in BatchNorm) ----------------
__global__ void finalize_bn(const float* __restrict__ colsum,
                            const float* __restrict__ colsumsq,
                            const float* __restrict__ gamma,
                            const float* __restrict__ beta,
                            float* __restrict__ scale, float* __restrict__ shift) {
    int c = threadIdx.x;
    float mean = colsum[c] * (1.0f / N_NODES);
    float var = colsumsq[c] * (1.0f / N_NODES) - mean * mean;
    float sc = gamma[c] * rsqrtf(var + BN_EPS);
    scale[c] = sc;
    shift[c] = beta[c] - mean * sc;
}

// ---------------- normalize + ReLU (in place on d_out) ----------------
__global__ __launch_bounds__(256) void normalize_relu(float* __restrict__ out,
                                                      const float* __restrict__ scale,
                                                      const float* __restrict__ shift) {
    const int total = N_NODES * 32;  // float4 count
    float4* o4 = (float4*)out;
    const float4* sc4 = (const float4*)scale;
    const float4* sh4 = (const float4*)shift;
    for (int i = blockIdx.x * blockDim.x + threadIdx.x; i < total;
         i += gridDim.x * blockDim.x) {
        int cg = i & 31;
        float4 v = o4[i];
        float4 sc = sc4[cg];
        float4 sh = sh4[cg];
        v.x = fmaxf(fmaf(v.x, sc.x, sh.x), 0.f);
        v.y = fmaxf(fmaf(v.y, sc.y, sh.y), 0.f);
        v.z = fmaxf(fmaf(v.z, sc.z, sh.z), 0.f);
        v.w = fmaxf(fmaf(v.w, sc.w, sh.w), 0.f);
        o4[i] = v;
    }
}

extern "C" void kernel_launch(void* const* d_in, const int* in_sizes, int n_in,
                              void* d_out, int out_size, void* d_ws, size_t ws_size,
                              hipStream_t stream) {
    const float* x = (const float*)d_in[0];
    const float* Wm = (const float*)d_in[1];
    // d_in[2] = b : cancels exactly in BatchNorm -> unused
    const float* gamma = (const float*)d_in[3];
    const float* beta = (const float*)d_in[4];
    const void* ei = d_in[5];

    float* out = (float*)d_out;  // holds agg_x, then final

    // workspace layout: eb first (8B aligned at base), then int/float arrays
    int2* eb = (int2*)d_ws;                 // E pairs (6.4 MB)
    int* deg = (int*)(eb + N_EDGES);        // N
    int* rp = deg + N_NODES;                // N+1
    int* fp = rp + N_NODES + 1;             // N
    int* bsum = fp + N_NODES;               // 128
    float* dis = (float*)(bsum + 128);      // N
    float* colsum = dis + N_NODES;          // 128
    float* colsumsq = colsum + 128;         // 128
    float* scale = colsumsq + 128;          // 128
    float* shift = scale + 128;             // 128
    int* flag = (int*)(shift + 128);        // 1

    hipMemsetAsync(deg, 0, (size_t)N_NODES * sizeof(int), stream);
    hipMemsetAsync(colsum, 0, 256 * sizeof(float), stream);

    detect_i64<<<1, 256, 0, stream>>>((const unsigned int*)ei, flag);
    count_deg_i<<<2048, 256, 0, stream>>>(ei, flag, deg);
    scan1<<<SCAN_NB, 256, 0, stream>>>(deg, rp, bsum);
    scan2<<<1, 128, 0, stream>>>(bsum, rp);
    scan3<<<(N_NODES + 255) / 256, 256, 0, stream>>>(rp, bsum, fp, deg, dis);
    fill_csr<<<2048, 256, 0, stream>>>(ei, flag, fp, dis, eb);
    gather_x<<<2048, 256, 0, stream>>>(rp, eb, dis, x, out);
    gemm_stats<<<(N_NODES + 63) / 64, 256, 0, stream>>>(out, Wm, colsum, colsumsq);
    finalize_bn<<<1, 128, 0, stream>>>(colsum, colsumsq, gamma, beta, scale, shift);
    normalize_relu<<<2048, 256, 0, stream>>>(out, scale, shift);
}

// Round 10
// 355.784 us; speedup vs baseline: 1.1252x; 1.1252x over previous
//
#include <hip/hip_runtime.h>

// R10: R9 (zero-LDS gemm) regressed 81->117us (serialized L2/HBM latency).
// Revert to LDS tiling + make it a 2-phase async pipeline: double-buffered
// 24KB chunks staged via global_load_lds (16B), issued BEFORE computing the
// current chunk so ~900cy HBM staging latency hides under ~2000cy compute.

#define N_NODES 100000
#define N_EDGES 800000
#define D 128
#define BN_EPS 1e-5f
#define SCAN_NB 98  // ceil(100000/1024)

typedef const __attribute__((address_space(1))) void* gas_ptr;
typedef __attribute__((address_space(3))) void* las_ptr;

__device__ __forceinline__ void gload16(const float* g, void* l) {
    __builtin_amdgcn_global_load_lds((gas_ptr)(const void*)g, (las_ptr)l, 16, 0, 0);
}

// ---------------- edge-index dtype hedge (int32 vs int64) ----------------
__global__ void detect_i64(const unsigned int* ei, int* flag) {
    __shared__ int nonzero;
    if (threadIdx.x == 0) nonzero = 0;
    __syncthreads();
    int local = 0;
    for (int i = threadIdx.x; i < 2048; i += 256)
        if (ei[2 * i + 1] != 0u) local = 1;
    if (local) atomicOr(&nonzero, 1);
    __syncthreads();
    if (threadIdx.x == 0) *flag = (nonzero == 0) ? 1 : 0;  // 1 => int64
}

__device__ __forceinline__ int edge_at(const void* ei, int is64, long long pos) {
    if (is64) return (int)((const long long*)ei)[pos];
    return ((const int*)ei)[pos];
}

// ---------------- degree histogram (int atomics) ----------------
__global__ void count_deg_i(const void* ei, const int* __restrict__ flag,
                            int* __restrict__ deg) {
    int is64 = *flag;
    for (int i = blockIdx.x * blockDim.x + threadIdx.x; i < N_EDGES;
         i += gridDim.x * blockDim.x) {
        int d = edge_at(ei, is64, (long long)N_EDGES + i);
        atomicAdd(&deg[d], 1);
    }
}

// ---------------- 3-kernel exclusive scan over deg -> rp ----------------
__global__ __launch_bounds__(256) void scan1(const int* __restrict__ deg,
                                             int* __restrict__ rp,
                                             int* __restrict__ bsum) {
    __shared__ int wsum[4];
    int tid = threadIdx.x;
    int base = blockIdx.x * 1024;
    int v[4];
#pragma unroll
    for (int i = 0; i < 4; ++i) {
        int idx = base + tid * 4 + i;
        v[i] = (idx < N_NODES) ? deg[idx] : 0;
    }
    int tsum = v[0] + v[1] + v[2] + v[3];
    int lane = tid & 63;
    int incl = tsum;
#pragma unroll
    for (int off = 1; off < 64; off <<= 1) {
        int n = __shfl_up(incl, off, 64);
        if (lane >= off) incl += n;
    }
    int wid = tid >> 6;
    if (lane == 63) wsum[wid] = incl;
    __syncthreads();
    int woff = 0;
    for (int w = 0; w < wid; ++w) woff += wsum[w];
    int run = woff + incl - tsum;  // exclusive prefix for this thread
#pragma unroll
    for (int i = 0; i < 4; ++i) {
        int idx = base + tid * 4 + i;
        if (idx < N_NODES) rp[idx] = run;
        run += v[i];
    }
    if (tid == 255) bsum[blockIdx.x] = woff + incl;  // block total
}

__global__ void scan2(int* __restrict__ bsum, int* __restrict__ rp) {
    __shared__ int s[128];
    int t = threadIdx.x;
    if (t < SCAN_NB) s[t] = bsum[t];
    __syncthreads();
    if (t == 0) {
        int run = 0;
        for (int i = 0; i < SCAN_NB; ++i) { int x = s[i]; s[i] = run; run += x; }
        rp[N_NODES] = N_EDGES;
    }
    __syncthreads();
    if (t < SCAN_NB) bsum[t] = s[t];
}

__global__ void scan3(int* __restrict__ rp, const int* __restrict__ bsum,
                      int* __restrict__ fp, const int* __restrict__ deg,
                      float* __restrict__ dis) {
    int idx = blockIdx.x * 256 + threadIdx.x;
    if (idx < N_NODES) {
        int v = rp[idx] + bsum[idx >> 10];
        rp[idx] = v;
        fp[idx] = v;
        dis[idx] = rsqrtf((float)deg[idx] + 1.0f);  // +1 self loop
    }
}

// ---------------- bucket fill: eb[rp[d]..] = (src, dis[s]*dis[d]) ----------------
__global__ void fill_csr(const void* ei, const int* __restrict__ flag,
                         int* __restrict__ fp, const float* __restrict__ dis,
                         int2* __restrict__ eb) {
    int is64 = *flag;
    for (int e = blockIdx.x * blockDim.x + threadIdx.x; e < N_EDGES;
         e += gridDim.x * blockDim.x) {
        int s = edge_at(ei, is64, e);
        int d = edge_at(ei, is64, (long long)N_EDGES + e);
        float coef = dis[s] * dis[d];
        int pos = atomicAdd(&fp[d], 1);
        eb[pos] = make_int2(s, __float_as_int(coef));
    }
}

// ---------------- gather: aggx[d] = sum_e coef*x[s] + dis[d]^2*x[d] ----------------
// one 64-lane wave per node, float2 per lane; 4-deep edge pipeline.
__global__ __launch_bounds__(256) void gather_x(const int* __restrict__ rp,
                                                const int2* __restrict__ eb,
                                                const float* __restrict__ dis,
                                                const float* __restrict__ x,
                                                float* __restrict__ aggx) {
    int lane = threadIdx.x & 63;
    int wid = threadIdx.x >> 6;
    const float2* x2 = (const float2*)x;
    for (int node = blockIdx.x * 4 + wid; node < N_NODES;
         node += gridDim.x * 4) {
        int beg = rp[node], end = rp[node + 1];
        float dd = dis[node];
        float2 xv = x2[(size_t)node * 64 + lane];
        float c2 = dd * dd;
        float a0 = xv.x * c2, a1 = xv.y * c2;
        int j = beg;
        for (; j + 4 <= end; j += 4) {
            int2 e0 = eb[j], e1 = eb[j + 1], e2 = eb[j + 2], e3 = eb[j + 3];
            float2 v0 = x2[(size_t)e0.x * 64 + lane];
            float2 v1 = x2[(size_t)e1.x * 64 + lane];
            float2 v2 = x2[(size_t)e2.x * 64 + lane];
            float2 v3 = x2[(size_t)e3.x * 64 + lane];
            float c0 = __int_as_float(e0.y), c1 = __int_as_float(e1.y);
            float cc = __int_as_float(e2.y), c3 = __int_as_float(e3.y);
            a0 = fmaf(v0.x, c0, a0); a1 = fmaf(v0.y, c0, a1);
            a0 = fmaf(v1.x, c1, a0); a1 = fmaf(v1.y, c1, a1);
            a0 = fmaf(v2.x, cc, a0); a1 = fmaf(v2.y, cc, a1);
            a0 = fmaf(v3.x, c3, a0); a1 = fmaf(v3.y, c3, a1);
        }
        for (; j < end; ++j) {
            int2 e = eb[j];
            float2 v = x2[(size_t)e.x * 64 + lane];
            float c = __int_as_float(e.y);
            a0 = fmaf(v.x, c, a0); a1 = fmaf(v.y, c, a1);
        }
        ((float2*)aggx)[(size_t)node * 64 + lane] = make_float2(a0, a1);
    }
}

// ---------------- in-place GEMM d_out = d_out @ W, fused column stats ----------------
// 2-phase async pipeline: stage chunk t+1 via global_load_lds while computing
// chunk t from the other LDS buffer. __syncthreads at iteration end drains
// vmcnt, but the loads have had the whole compute phase to land.
// LDS: 2 x (A 8KB + W 16KB) = 48KB -> 3 blocks/CU.
__global__ __launch_bounds__(256) void gemm_stats(float* __restrict__ ax,
                                                  const float* __restrict__ Wm,
                                                  float* __restrict__ colsum,
                                                  float* __restrict__ colsumsq) {
    __shared__ float Abuf[2][64 * 32];    // 8 KB per buffer
    __shared__ float Wbuf[2][32 * 128];   // 16 KB per buffer
    int tid = threadIdx.x;
    int tx = tid & 31;
    int ty = tid >> 5;       // 0..7, 8 rows each
    int wid = tid >> 6;      // wave 0..3
    int lane = tid & 63;
    int row0 = blockIdx.x * 64;

    // stage chunk [kc, kc+32) into buffer b. LDS dest is wave-uniform base +
    // lane*16 (global_load_lds semantics); global source is per-lane.
    auto stage = [&](int b, int kc) {
#pragma unroll
        for (int i = 0; i < 2; ++i) {  // A: 8 segments of 1KB, wave w owns w*2+i
            int seg = wid * 2 + i;
            int idx = seg * 64 + lane;        // float4 index 0..511
            int row = idx >> 3, c4 = idx & 7;
            int gr = row0 + row;
            if (gr >= N_NODES) gr = N_NODES - 1;  // clamp; masked later
            const float* src = ax + (size_t)gr * 128 + kc + c4 * 4;
            gload16(src, (char*)&Abuf[b][0] + seg * 1024);
        }
#pragma unroll
        for (int i = 0; i < 4; ++i) {  // W: 16 segments of 1KB, wave w owns w*4+i
            int seg = wid * 4 + i;
            int idx = seg * 64 + lane;        // float4 index 0..1023
            const float* src = Wm + (size_t)kc * 128 + (size_t)idx * 4;
            gload16(src, (char*)&Wbuf[b][0] + seg * 1024);
        }
    };

    stage(0, 0);
    __syncthreads();  // drains vmcnt(0): chunk 0 landed (cold, exposed once)

    float acc[8][4] = {};

#pragma unroll 1
    for (int t = 0; t < 4; ++t) {
        if (t < 3) stage((t + 1) & 1, (t + 1) * 32);  // issue next chunk FIRST
        asm volatile("" ::: "memory");  // keep stage issues above the compute
        const float4* As4 = (const float4*)Abuf[t & 1];
        const float4* Ws4 = (const float4*)Wbuf[t & 1];
        for (int k4 = 0; k4 < 32; k4 += 4) {
            float4 a8[8];
#pragma unroll
            for (int r = 0; r < 8; ++r)
                a8[r] = As4[(ty * 8 + r) * 8 + (k4 >> 2)];
#pragma unroll
            for (int kk = 0; kk < 4; ++kk) {
                float4 w = Ws4[(k4 + kk) * 32 + tx];
#pragma unroll
                for (int r = 0; r < 8; ++r) {
                    float av = (kk == 0) ? a8[r].x : (kk == 1) ? a8[r].y
                             : (kk == 2) ? a8[r].z : a8[r].w;
                    acc[r][0] = fmaf(av, w.x, acc[r][0]);
                    acc[r][1] = fmaf(av, w.y, acc[r][1]);
                    acc[r][2] = fmaf(av, w.z, acc[r][2]);
                    acc[r][3] = fmaf(av, w.w, acc[r][3]);
                }
            }
        }
        __syncthreads();  // drains vmcnt: chunk t+1 landed (hidden under compute)
    }

    // write back (in place; own rows only -> race-free)
#pragma unroll
    for (int r = 0; r < 8; ++r) {
        int gr = row0 + ty * 8 + r;
        if (gr < N_NODES)
            ((float4*)&ax[(size_t)gr * 128])[tx] =
                make_float4(acc[r][0], acc[r][1], acc[r][2], acc[r][3]);
    }

    // fused BN column stats (clamped OOB rows masked to 0)
    float ps[4] = {0.f, 0.f, 0.f, 0.f}, pq[4] = {0.f, 0.f, 0.f, 0.f};
#pragma unroll
    for (int r = 0; r < 8; ++r) {
        int gr = row0 + ty * 8 + r;
        float m = (gr < N_NODES) ? 1.0f : 0.0f;
#pragma unroll
        for (int k = 0; k < 4; ++k) {
            float v = acc[r][k] * m;
            ps[k] += v;
            pq[k] += v * v;
        }
    }
    // combine tid with tid^32 (same tx, different ty) in-wave
#pragma unroll
    for (int k = 0; k < 4; ++k) {
        ps[k] += __shfl_xor(ps[k], 32);
        pq[k] += __shfl_xor(pq[k], 32);
    }
    float* red = (float*)Abuf;  // reuse 8KB of LDS (all compute done)
    if ((tid & 32) == 0) {
#pragma unroll
        for (int k = 0; k < 4; ++k) {
            red[wid * 128 + tx * 4 + k] = ps[k];
            red[1024 + wid * 128 + tx * 4 + k] = pq[k];
        }
    }
    __syncthreads();
    if (tid < 128) {
        float s = 0.f, q = 0.f;
#pragma unroll
        for (int w = 0; w < 4; ++w) {
            s += red[w * 128 + tid];
            q += red[1024 + w * 128 + tid];
        }
        atomicAdd(&colsum[tid], s);
        atomicAdd(&colsumsq[tid], q);
    }
}

// ---------------- BN params (b cancels exactly in BatchNorm) ----------------
__global__ void finalize_bn(const float* __restrict__ colsum,
                            const float* __restrict__ colsumsq,
                            const float* __restrict__ gamma,
                            const float* __restrict__ beta,
                            float* __restrict__ scale, float* __restrict__ shift) {
    int c = threadIdx.x;
    float mean = colsum[c] * (1.0f / N_NODES);
    float var = colsumsq[c] * (1.0f / N_NODES) - mean * mean;
    float sc = gamma[c] * rsqrtf(var + BN_EPS);
    scale[c] = sc;
    shift[c] = beta[c] - mean * sc;
}

// ---------------- normalize + ReLU (in place on d_out) ----------------
__global__ __launch_bounds__(256) void normalize_relu(float* __restrict__ out,
                                                      const float* __restrict__ scale,
                                                      const float* __restrict__ shift) {
    const int total = N_NODES * 32;  // float4 count
    float4* o4 = (float4*)out;
    const float4* sc4 = (const float4*)scale;
    const float4* sh4 = (const float4*)shift;
    for (int i = blockIdx.x * blockDim.x + threadIdx.x; i < total;
         i += gridDim.x * blockDim.x) {
        int cg = i & 31;
        float4 v = o4[i];
        float4 sc = sc4[cg];
        float4 sh = sh4[cg];
        v.x = fmaxf(fmaf(v.x, sc.x, sh.x), 0.f);
        v.y = fmaxf(fmaf(v.y, sc.y, sh.y), 0.f);
        v.z = fmaxf(fmaf(v.z, sc.z, sh.z), 0.f);
        v.w = fmaxf(fmaf(v.w, sc.w, sh.w), 0.f);
        o4[i] = v;
    }
}

extern "C" void kernel_launch(void* const* d_in, const int* in_sizes, int n_in,
                              void* d_out, int out_size, void* d_ws, size_t ws_size,
                              hipStream_t stream) {
    const float* x = (const float*)d_in[0];
    const float* Wm = (const float*)d_in[1];
    // d_in[2] = b : cancels exactly in BatchNorm -> unused
    const float* gamma = (const float*)d_in[3];
    const float* beta = (const float*)d_in[4];
    const void* ei = d_in[5];

    float* out = (float*)d_out;  // holds agg_x, then final

    // workspace layout: eb first (8B aligned at base), then int/float arrays
    int2* eb = (int2*)d_ws;                 // E pairs (6.4 MB)
    int* deg = (int*)(eb + N_EDGES);        // N
    int* rp = deg + N_NODES;                // N+1
    int* fp = rp + N_NODES + 1;             // N
    int* bsum = fp + N_NODES;               // 128
    float* dis = (float*)(bsum + 128);      // N
    float* colsum = dis + N_NODES;          // 128
    float* colsumsq = colsum + 128;         // 128
    float* scale = colsumsq + 128;          // 128
    float* shift = scale + 128;             // 128
    int* flag = (int*)(shift + 128);        // 1

    hipMemsetAsync(deg, 0, (size_t)N_NODES * sizeof(int), stream);
    hipMemsetAsync(colsum, 0, 256 * sizeof(float), stream);

    detect_i64<<<1, 256, 0, stream>>>((const unsigned int*)ei, flag);
    count_deg_i<<<2048, 256, 0, stream>>>(ei, flag, deg);
    scan1<<<SCAN_NB, 256, 0, stream>>>(deg, rp, bsum);
    scan2<<<1, 128, 0, stream>>>(bsum, rp);
    scan3<<<(N_NODES + 255) / 256, 256, 0, stream>>>(rp, bsum, fp, deg, dis);
    fill_csr<<<2048, 256, 0, stream>>>(ei, flag, fp, dis, eb);
    gather_x<<<2048, 256, 0, stream>>>(rp, eb, dis, x, out);
    gemm_stats<<<(N_NODES + 63) / 64, 256, 0, stream>>>(out, Wm, colsum, colsumsq);
    finalize_bn<<<1, 128, 0, stream>>>(colsum, colsumsq, gamma, beta, scale, shift);
    normalize_relu<<<2048, 256, 0, stream>>>(out, scale, shift);
}